// Round 6
// baseline (342.937 us; speedup 1.0000x reference)
//
#include <hip/hip_runtime.h>
#include <hip/hip_bf16.h>

// CapsuleLayer dynamic routing, MI355X.
// B=32,N=2048,D=32 inputs; C=64,V=32 output caps; 3 routing rounds.
// u_hat computed once via bf16 MFMA -> ws (bf16 [n][b][p], 256MB);
// each routing round = one fused pass over u_hat (agree -> softmax -> s-accum),
// using linearity of agreement: b_logits = u_hat . (v1+v2+...).
// Round 6: operand-swapped MFMA (A=W rows=p, B=x cols=b) so D gives each lane
// 4 consecutive p for one b-row = one aligned 8B store. Eliminates the whole
// LDS transpose round-trip (256 ds_write + 2 lgkmcnt(0) drains per phase) that
// serialized r3/r5. No LDS -> occupancy cap moves to VGPR (~2x waves/CU).
// 2-deep W prefetch ring, compile-time indices, no fences.

#define B_ 32
#define N_ 2048
#define D_ 32
#define C_ 64
#define V_ 32

typedef __attribute__((ext_vector_type(4))) float f32x4;
typedef __attribute__((ext_vector_type(4))) int i32x4;
typedef __attribute__((ext_vector_type(2))) int i32x2;
typedef __bf16 bf16x8 __attribute__((ext_vector_type(8)));

__device__ __forceinline__ unsigned f2bf1(float f) {
  unsigned u = __builtin_bit_cast(unsigned, f);
  return (u + 0x7FFFu + ((u >> 16) & 1u)) >> 16;  // RNE
}
__device__ __forceinline__ float bf2f(unsigned h) {
  unsigned u = h << 16;
  return __builtin_bit_cast(float, u);
}

__device__ __forceinline__ bf16x8 cvt_frag(f32x4 lo, f32x4 hi) {
  i32x4 r;
  r[0] = f2bf1(lo[0]) | (f2bf1(lo[1]) << 16);
  r[1] = f2bf1(lo[2]) | (f2bf1(lo[3]) << 16);
  r[2] = f2bf1(hi[0]) | (f2bf1(hi[1]) << 16);
  r[3] = f2bf1(hi[2]) | (f2bf1(hi[3]) << 16);
  return __builtin_bit_cast(bf16x8, r);
}

// u_hat[n][b][p] (p=c*32+v), bf16. Block = one n, 4 waves; wave owns 512 p.
// Per p-tile (16 p): A-frag = W rows (lane l16 = p-row), B-frag = x cols
// (lane l16 = b). D: col=lane=b, row=kg*4+j = 4 consecutive p -> 8B store.
__global__ __launch_bounds__(256) void uhat_kernel(const float* __restrict__ x,
                                                   const float* __restrict__ W,
                                                   unsigned short* __restrict__ uh) {
  const int n = blockIdx.x;
  const int wave = threadIdx.x >> 6;
  const int l = threadIdx.x & 63;
  const int l16 = l & 15, kg = l >> 4;  // frag: row/col = l16, k = kg*8 + i

  // B-operand = x: lane l16 = col b (+16 per bt), elems k = kg*8..kg*8+7
  bf16x8 xb[2];
#pragma unroll
  for (int bt = 0; bt < 2; ++bt) {
    const float* xp = x + (((size_t)(bt * 16 + l16)) * N_ + n) * D_ + kg * 8;
    xb[bt] = cvt_frag(*(const f32x4*)xp, *(const f32x4*)(xp + 4));
  }
  const f32x4 zero = {0.f, 0.f, 0.f, 0.f};
  // A-operand = W: lane l16 = row p = wave*512 + pt*16 + l16
  const float* wbase = W + ((size_t)n * 2048 + wave * 512 + l16) * D_ + kg * 8;
  // store base: + b*2048 + pt*16 (+ j via the 8B vector)
  unsigned short* ubase = uh + (size_t)n * 65536 + (size_t)(wave * 512 + kg * 4);

  // 2-deep prefetch ring (all indices compile-time via full unroll)
  f32x4 wl[2][2];
  {
    const float* w0 = wbase;
    const float* w1 = wbase + (size_t)16 * D_;
    wl[0][0] = *(const f32x4*)w0; wl[0][1] = *(const f32x4*)(w0 + 4);
    wl[1][0] = *(const f32x4*)w1; wl[1][1] = *(const f32x4*)(w1 + 4);
  }
#pragma unroll
  for (int pt = 0; pt < 32; ++pt) {
    f32x4 c0 = wl[pt & 1][0], c1 = wl[pt & 1][1];
    if (pt < 30) {
      const float* wp = wbase + (size_t)((pt + 2) * 16) * D_;
      wl[pt & 1][0] = *(const f32x4*)wp;
      wl[pt & 1][1] = *(const f32x4*)(wp + 4);
    }
    bf16x8 wfrag = cvt_frag(c0, c1);
#pragma unroll
    for (int bt = 0; bt < 2; ++bt) {
      f32x4 acc = __builtin_amdgcn_mfma_f32_16x16x32_bf16(wfrag, xb[bt], zero, 0, 0, 0);
      i32x2 dv;
      dv[0] = (int)(f2bf1(acc[0]) | (f2bf1(acc[1]) << 16));
      dv[1] = (int)(f2bf1(acc[2]) | (f2bf1(acc[3]) << 16));
      *(i32x2*)(ubase + (size_t)(bt * 16 + l16) * 2048 + pt * 16) = dv;
    }
  }
}

// Routing pass: s[b,c,v] = sum_n softmax_c(u_hat[b,n,:,:].vsum[b,:,:])[c] * u_hat[b,n,c,v]
// wave lane l == c. Block = 4 waves x 16 n, same b. Partials (no atomics) to ws.
template <int ROUND>
__global__ __launch_bounds__(256) void routing_kernel(const unsigned short* __restrict__ uh,
                                                      const float* __restrict__ vsum,
                                                      float* __restrict__ part) {
  const int b = blockIdx.x >> 5;  // 32 chunks per b
  const int chunk = blockIdx.x & 31;
  const int wave = threadIdx.x >> 6;
  const int l = threadIdx.x & 63;  // = c

  float vs[32];
  if (ROUND >= 2) {
    const f32x4* vp = (const f32x4*)(vsum + ((size_t)b * 64 + l) * 32);
#pragma unroll
    for (int i = 0; i < 8; ++i) {
      f32x4 t = vp[i];
      vs[4 * i] = t[0]; vs[4 * i + 1] = t[1]; vs[4 * i + 2] = t[2]; vs[4 * i + 3] = t[3];
    }
  }
  float sacc[32];
#pragma unroll
  for (int v = 0; v < 32; ++v) sacc[v] = 0.f;

  const int n0 = chunk * 64 + wave * 16;
  for (int ni = 0; ni < 16; ++ni) {
    const int n = n0 + ni;
    const i32x4* up = (const i32x4*)(uh + ((size_t)n * 32 + b) * 2048 + l * 32);
    i32x4 qs0 = up[0], qs1 = up[1], qs2 = up[2], qs3 = up[3];
    float u[32];
#pragma unroll
    for (int i = 0; i < 4; ++i) {
      unsigned v0 = (unsigned)qs0[i], v1 = (unsigned)qs1[i], v2 = (unsigned)qs2[i], v3 = (unsigned)qs3[i];
      u[0 + 2 * i] = bf2f(v0 & 0xffffu);  u[0 + 2 * i + 1] = bf2f(v0 >> 16);
      u[8 + 2 * i] = bf2f(v1 & 0xffffu);  u[8 + 2 * i + 1] = bf2f(v1 >> 16);
      u[16 + 2 * i] = bf2f(v2 & 0xffffu); u[16 + 2 * i + 1] = bf2f(v2 >> 16);
      u[24 + 2 * i] = bf2f(v3 & 0xffffu); u[24 + 2 * i + 1] = bf2f(v3 >> 16);
    }
    float r;
    if (ROUND >= 2) {
      float br = 0.f;
#pragma unroll
      for (int v = 0; v < 32; ++v) br = fmaf(u[v], vs[v], br);
      float m = br;
#pragma unroll
      for (int off = 32; off; off >>= 1) m = fmaxf(m, __shfl_xor(m, off, 64));
      float e = __expf(br - m);
      float den = e;
#pragma unroll
      for (int off = 32; off; off >>= 1) den += __shfl_xor(den, off, 64);
      r = e / den;
    } else {
      r = 1.0f / 64.0f;  // softmax of zeros
    }
#pragma unroll
    for (int v = 0; v < 32; ++v) sacc[v] = fmaf(r, u[v], sacc[v]);
  }

  __shared__ float red[4][64][33];  // +1 pad: conflict-free
#pragma unroll
  for (int v = 0; v < 32; ++v) red[wave][l][v] = sacc[v];
  __syncthreads();
  const int t = threadIdx.x;
  f32x4 o0, o1;
#pragma unroll
  for (int i = 0; i < 4; ++i) {
    const int e0 = t * 8 + i, e1 = t * 8 + 4 + i;
    o0[i] = red[0][e0 >> 5][e0 & 31] + red[1][e0 >> 5][e0 & 31] +
            red[2][e0 >> 5][e0 & 31] + red[3][e0 >> 5][e0 & 31];
    o1[i] = red[0][e1 >> 5][e1 & 31] + red[1][e1 >> 5][e1 & 31] +
            red[2][e1 >> 5][e1 & 31] + red[3][e1 >> 5][e1 & 31];
  }
  float* pp = part + ((size_t)blockIdx.x) * 2048 + t * 8;
  *(f32x4*)pp = o0;
  *(f32x4*)(pp + 4) = o1;
}

// Reduce partials -> s, squash -> v. Writes v to out; maintains vsum for agreement.
template <int ROUND>
__global__ __launch_bounds__(256) void squash_kernel(const float* __restrict__ part,
                                                     float* __restrict__ vsum,
                                                     float* __restrict__ out) {
  const int t = blockIdx.x * 256 + threadIdx.x;  // 0..65535 = b*2048 + c*32 + v
  const int b = t >> 11;
  const int e = t & 2047;
  float sv = 0.f;
#pragma unroll
  for (int k = 0; k < 32; ++k) sv += part[((size_t)(b * 32 + k)) * 2048 + e];
  float sq = sv * sv;
#pragma unroll
  for (int off = 16; off; off >>= 1) sq += __shfl_xor(sq, off, 64);  // sum over v (32-lane groups)
  float scale = (sq / (1.f + sq)) * rsqrtf(sq + 1e-9f);
  float val = sv * scale;
  out[t] = val;
  if (ROUND == 1) vsum[t] = val;
  else if (ROUND == 2) vsum[t] += val;
}

extern "C" void kernel_launch(void* const* d_in, const int* in_sizes, int n_in,
                              void* d_out, int out_size, void* d_ws, size_t ws_size,
                              hipStream_t stream) {
  const float* x = (const float*)d_in[0];  // [B,N,D]
  const float* W = (const float*)d_in[1];  // [1,N,C,V,D]
  float* out = (float*)d_out;              // [B,1,C,V,1] = 65536 fp32

  const size_t UH_BYTES = (size_t)B_ * N_ * C_ * V_ * 2;  // 268435456
  const size_t PART_BYTES = (size_t)B_ * 32 * 2048 * 4;   // 8388608
  const size_t VSUM_BYTES = (size_t)B_ * C_ * V_ * 4;     // 262144
  if (ws_size < UH_BYTES + PART_BYTES + VSUM_BYTES) return;  // can't run

  unsigned short* uh = (unsigned short*)d_ws;
  float* part = (float*)((char*)d_ws + UH_BYTES);
  float* vsum = (float*)((char*)d_ws + UH_BYTES + PART_BYTES);

  uhat_kernel<<<N_, 256, 0, stream>>>(x, W, uh);
  routing_kernel<1><<<B_ * 32, 256, 0, stream>>>(uh, vsum, part);
  squash_kernel<1><<<256, 256, 0, stream>>>(part, vsum, out);
  routing_kernel<2><<<B_ * 32, 256, 0, stream>>>(uh, vsum, part);
  squash_kernel<2><<<256, 256, 0, stream>>>(part, vsum, out);
  routing_kernel<3><<<B_ * 32, 256, 0, stream>>>(uh, vsum, part);
  squash_kernel<3><<<256, 256, 0, stream>>>(part, vsum, out);
}